// Round 7
// baseline (235.214 us; speedup 1.0000x reference)
//
#include <hip/hip_runtime.h>

#define N_NODES 100000
#define D 64
#define BIN_ROWS 64
#define NBINS 1563          // ceil(100000 / 64)
#define PE 4096             // edges per partition block -> 245 blocks
#define XW_BLOCKS 3125

typedef unsigned int u32;

__device__ __forceinline__ float bf16_to_f32(unsigned short u) {
    union { u32 i; float f; } c; c.i = ((u32)u) << 16; return c.f;
}
__device__ __forceinline__ unsigned short f32_to_bf16(float f) {
    union { float f; u32 i; } c; c.f = f;
    const u32 u = c.i;
    return (unsigned short)((u + 0x7FFFu + ((u >> 16) & 1u)) >> 16);
}

// ---------------- y = bf16(x @ W^T), W register-resident; edge hist folded in ----------------
__global__ __launch_bounds__(256) void xw_kernel(const float* __restrict__ x,
                                                 const float* __restrict__ W,
                                                 const int* __restrict__ erow,
                                                 int* __restrict__ binCounts, int ne,
                                                 unsigned short* __restrict__ y) {
    __shared__ float Ws[D * 68];     // row stride 68 floats (272 B): 16B-aligned b128, full-bank spread
    __shared__ float xs[32][D];
    const int tid = threadIdx.x;

    // coalesced W load -> strided LDS
    for (int i = tid; i < D * D; i += 256) Ws[(i >> 6) * 68 + (i & 63)] = W[i];

    // stage 32 nodes of x (N_NODES = 3125*32 exactly, no bounds needed)
    const int nodeBase = blockIdx.x * 32;
    for (int i = tid; i < 32 * D; i += 256)
        xs[i >> 6][i & 63] = x[(nodeBase + (i >> 6)) * D + (i & 63)];

    // folded edge histogram (grid-stride); binCounts pre-zeroed via hipMemsetAsync
    for (int e = blockIdx.x * 256 + tid; e < ne; e += XW_BLOCKS * 256)
        atomicAdd(&binCounts[erow[e] >> 6], 1);
    __syncthreads();

    // extract W row (lane j) into 64 VGPRs
    const int j = tid & 63;
    const int w = tid >> 6;
    float4 wr[16];
    const float4* WsRow = (const float4*)(Ws + j * 68);
#pragma unroll
    for (int k = 0; k < 16; ++k) wr[k] = WsRow[k];

    // each wave: 8 nodes, FMA-bound inner loop (x via LDS broadcast)
    for (int s = 0; s < 8; ++s) {
        const int local = w * 8 + s;
        const float4* xr = (const float4*)(&xs[local][0]);
        float a0 = 0.f, a1 = 0.f;
#pragma unroll
        for (int k = 0; k < 16; k += 2) {
            const float4 x0 = xr[k], x1 = xr[k + 1];
            a0 = fmaf(x0.x, wr[k].x, a0);     a0 = fmaf(x0.y, wr[k].y, a0);
            a0 = fmaf(x0.z, wr[k].z, a0);     a0 = fmaf(x0.w, wr[k].w, a0);
            a1 = fmaf(x1.x, wr[k+1].x, a1);   a1 = fmaf(x1.y, wr[k+1].y, a1);
            a1 = fmaf(x1.z, wr[k+1].z, a1);   a1 = fmaf(x1.w, wr[k+1].w, a1);
        }
        y[(nodeBase + local) * D + j] = f32_to_bf16(a0 + a1);
    }
}

// ---------------- single-block exclusive scan of 1563 bin counts ----------------
__global__ __launch_bounds__(512) void binscan_kernel(const int* __restrict__ binCounts,
                                                      int* __restrict__ binOff,
                                                      int* __restrict__ binCursor) {
    __shared__ int sdat[512];
    const int tid = threadIdx.x;
    int v[4], sum = 0;
#pragma unroll
    for (int k = 0; k < 4; ++k) {
        const int i = tid * 4 + k;
        v[k] = (i < NBINS) ? binCounts[i] : 0;
        sum += v[k];
    }
    sdat[tid] = sum;
    __syncthreads();
    for (int d = 1; d < 512; d <<= 1) {
        const int t = (tid >= d) ? sdat[tid - d] : 0;
        __syncthreads();
        sdat[tid] += t;
        __syncthreads();
    }
    int run = sdat[tid] - sum;
#pragma unroll
    for (int k = 0; k < 4; ++k) {
        const int i = tid * 4 + k;
        if (i < NBINS) { binOff[i] = run; binCursor[i] = run; }
        run += v[k];
    }
    if (tid == 511) binOff[NBINS] = sdat[511];
}

// ---------------- partition: pack (col,localrow,q9val) into u32, bin-grouped ----------------
__global__ __launch_bounds__(256) void partition_kernel(const int* __restrict__ erow,
                                                        const int* __restrict__ ecol,
                                                        const float* __restrict__ eval_,
                                                        int* __restrict__ binCursor,
                                                        u32* __restrict__ pedge, int ne) {
    __shared__ int h[NBINS];
    __shared__ int lcur[NBINS];
    for (int i = threadIdx.x; i < NBINS; i += 256) h[i] = 0;
    __syncthreads();
    const int base = blockIdx.x * PE;
    const int end  = min(base + PE, ne);
    for (int e = base + threadIdx.x; e < end; e += 256)
        atomicAdd(&h[erow[e] >> 6], 1);           // ds_add_u32 no-return
    __syncthreads();
    for (int i = threadIdx.x; i < NBINS; i += 256) {
        const int c = h[i];
        lcur[i] = c ? atomicAdd(&binCursor[i], c) : 0;
    }
    __syncthreads();
    for (int e = base + threadIdx.x; e < end; e += 256) {
        const int r = erow[e];
        const int bin = r >> 6;
        const int pos = atomicAdd(&lcur[bin], 1);
        int q = (int)(eval_[e] * 512.0f + 0.5f);
        q = (q > 511) ? 511 : q;
        pedge[pos] = ((u32)ecol[e] << 15) | ((u32)(r & 63) << 9) | (u32)q;
    }
}

// ---------------- aggregate: one block per 64-row bin, 16KB int LDS acc ----------------
__global__ __launch_bounds__(256) void aggregate_kernel(const int* __restrict__ binOff,
                                                        const u32* __restrict__ pedge,
                                                        const unsigned short* __restrict__ y,
                                                        const float* __restrict__ b,
                                                        float4* __restrict__ out4) {
    __shared__ int acc[BIN_ROWS * D];    // 16 KB
    const int tid = threadIdx.x;
    for (int i = tid; i < BIN_ROWS * D; i += 256) acc[i] = 0;
    __syncthreads();

    const int bin  = blockIdx.x;
    const int lane = tid & 63;
    const int w    = tid >> 6;
    const int s    = binOff[bin];
    const int e    = binOff[bin + 1];

    for (int bb0 = s + w * 16; bb0 < e; bb0 += 64) {
        const int bb = __builtin_amdgcn_readfirstlane(bb0);
        u32 u[16];
#pragma unroll
        for (int j = 0; j < 16; ++j) {          // wave-uniform -> scalar loads
            const int idx = bb + j;
            const u32 t = pedge[(idx < e) ? idx : (e - 1)];
            u[j] = (idx < e) ? t : 0u;          // pad decodes to vq=0 -> adds 0
        }
        unsigned short g[16];
#pragma unroll
        for (int j = 0; j < 16; ++j) {          // 16 concurrent 128B row gathers
            g[j] = y[(int)(u[j] >> 15) * D + lane];
        }
#pragma unroll
        for (int j = 0; j < 16; ++j) {
            const float vq = (float)(u[j] & 511u);          // val * 512
            const float yf = bf16_to_f32(g[j]);
            const int   qi = (int)(vq * yf * 512.0f);       // contribution * 2^18
            const int   r  = (int)((u[j] >> 9) & 63u);
            atomicAdd(&acc[r * D + lane], qi);              // ds_add_u32 (native)
        }
    }
    __syncthreads();

    const int rowBase = bin * BIN_ROWS;
    const float INV = 1.0f / 262144.0f;
    for (int i = tid; i < BIN_ROWS * 16; i += 256) {
        const int rl = i >> 4, q = i & 15;
        const int row = rowBase + rl;
        if (row < N_NODES) {
            const int4   a  = ((const int4*)acc)[i];
            const float4 bv = ((const float4*)b)[q];
            out4[row * 16 + q] = make_float4((float)a.x * INV + bv.x,
                                             (float)a.y * INV + bv.y,
                                             (float)a.z * INV + bv.z,
                                             (float)a.w * INV + bv.w);
        }
    }
}

// ---------------- fallback (small ws): atomic scatter ----------------
__global__ __launch_bounds__(256) void init_out_kernel(const float* __restrict__ b,
                                                       float* __restrict__ out) {
    const int i = blockIdx.x * blockDim.x + threadIdx.x;
    const int total4 = N_NODES * D / 4;
    if (i < total4) {
        const float4* b4 = reinterpret_cast<const float4*>(b);
        reinterpret_cast<float4*>(out)[i] = b4[i & 15];
    }
}

__global__ __launch_bounds__(256) void scatter_kernel(const int* __restrict__ erow,
                                                      const int* __restrict__ ecol,
                                                      const float* __restrict__ eval_,
                                                      const unsigned short* __restrict__ y,
                                                      float* __restrict__ out, int ne) {
    const int e    = blockIdx.x * 4 + (threadIdx.x >> 6);
    const int lane = threadIdx.x & 63;
    if (e >= ne) return;
    atomicAdd(&out[erow[e] * D + lane], eval_[e] * bf16_to_f32(y[ecol[e] * D + lane]));
}

extern "C" void kernel_launch(void* const* d_in, const int* in_sizes, int n_in,
                              void* d_out, int out_size, void* d_ws, size_t ws_size,
                              hipStream_t stream) {
    const float* x     = (const float*)d_in[0];
    const int*   erow  = (const int*)  d_in[1];
    const int*   ecol  = (const int*)  d_in[2];
    const float* eval_ = (const float*)d_in[3];
    const float* W     = (const float*)d_in[4];
    const float* b     = (const float*)d_in[5];
    float*       out   = (float*)d_out;
    const int ne = in_sizes[1];

    char* ws = (char*)d_ws;
    // workspace layout (256-aligned)
    const size_t Y_OFF     = 0;              // 100000*64*2 = 12,800,000 B
    const size_t PEDGE_OFF = 12800000;       // 1M * 4B = 4,000,000 B
    const size_t BCNT_OFF  = 16800000;       // 1563*4
    const size_t BOFF_OFF  = 16806400;       // 1564*4
    const size_t BCUR_OFF  = 16812800;       // 1563*4
    const size_t TOTAL     = 16819200;

    unsigned short* y = (unsigned short*)(ws + Y_OFF);

    if (ws_size >= TOTAL) {
        u32* pedge     = (u32*)(ws + PEDGE_OFF);
        int* binCounts = (int*)(ws + BCNT_OFF);
        int* binOff    = (int*)(ws + BOFF_OFF);
        int* binCursor = (int*)(ws + BCUR_OFF);

        // 0) zero bin counters (graph-capture-safe async memset)
        hipMemsetAsync(binCounts, 0, NBINS * sizeof(int), stream);

        // 1) y = bf16(x @ W^T) + folded edge histogram
        xw_kernel<<<XW_BLOCKS, 256, 0, stream>>>(x, W, erow, binCounts, ne, y);

        // 2) scan + partition (245 blocks)
        binscan_kernel<<<1, 512, 0, stream>>>(binCounts, binOff, binCursor);
        partition_kernel<<<(ne + PE - 1) / PE, 256, 0, stream>>>(erow, ecol, eval_, binCursor, pedge, ne);

        // 3) per-bin int-LDS-accumulated aggregation + bias
        aggregate_kernel<<<NBINS, 256, 0, stream>>>(binOff, pedge, y, b, (float4*)out);
    } else {
        xw_kernel<<<XW_BLOCKS, 256, 0, stream>>>(x, W, erow, (int*)d_out, 0, y);
        init_out_kernel<<<(N_NODES * D / 4 + 255) / 256, 256, 0, stream>>>(b, out);
        scatter_kernel<<<(ne + 3) / 4, 256, 0, stream>>>(erow, ecol, eval_, y, out, ne);
    }
}

// Round 8
// 141.005 us; speedup vs baseline: 1.6681x; 1.6681x over previous
//
#include <hip/hip_runtime.h>

#define N_NODES 100000
#define D 64
#define BIN_ROWS 64
#define NBINS 1563          // ceil(100000 / 64)
#define CPAD 16             // counter padding: one 64B line per counter
#define PE 8192             // edges per partition block -> 123 blocks

typedef unsigned int u32;

__device__ __forceinline__ float bf16_to_f32(unsigned short u) {
    union { u32 i; float f; } c; c.i = ((u32)u) << 16; return c.f;
}
__device__ __forceinline__ unsigned short f32_to_bf16(float f) {
    union { float f; u32 i; } c; c.f = f;
    const u32 u = c.i;
    return (unsigned short)((u + 0x7FFFu + ((u >> 16) & 1u)) >> 16);
}

// ---------------- y = bf16(x @ W^T) ----------------
__global__ __launch_bounds__(256) void xw_kernel(const float* __restrict__ x,
                                                 const float* __restrict__ W,
                                                 unsigned short* __restrict__ y) {
    __shared__ float Ws[D][D + 1];
    __shared__ float xs[32][D];
    const int tid = threadIdx.x;

    for (int i = tid; i < D * D; i += 256) Ws[i >> 6][i & 63] = W[i];

    const int nodeBase = blockIdx.x * 32;     // N_NODES = 3125*32 exactly
    for (int i = tid; i < 32 * D; i += 256)
        xs[i >> 6][i & 63] = x[(nodeBase + (i >> 6)) * D + (i & 63)];
    __syncthreads();

    const int wave = tid >> 6, j = tid & 63;
    for (int s = 0; s < 8; ++s) {
        const int local = wave * 8 + s;
        float acc = 0.f;
#pragma unroll
        for (int k = 0; k < D; ++k) acc += xs[local][k] * Ws[j][k];
        y[(nodeBase + local) * D + j] = f32_to_bf16(acc);
    }
}

// ---------------- per-block LDS histogram of row>>6, flush to PADDED counters ----------------
__global__ __launch_bounds__(256) void binhist_kernel(const int* __restrict__ erow,
                                                      int* __restrict__ binCounts, int ne) {
    __shared__ int h[NBINS];
    for (int i = threadIdx.x; i < NBINS; i += 256) h[i] = 0;
    __syncthreads();
    const int stride = gridDim.x * 256;
    for (int e = blockIdx.x * 256 + threadIdx.x; e < ne; e += stride)
        atomicAdd(&h[erow[e] >> 6], 1);
    __syncthreads();
    for (int i = threadIdx.x; i < NBINS; i += 256)
        if (h[i]) atomicAdd(&binCounts[i * CPAD], h[i]);   // one line per counter
}

// ---------------- single-block exclusive scan (padded in, dense off + padded cursor) ----------------
__global__ __launch_bounds__(512) void binscan_kernel(const int* __restrict__ binCounts,
                                                      int* __restrict__ binOff,
                                                      int* __restrict__ binCursor) {
    __shared__ int sdat[512];
    const int tid = threadIdx.x;
    int v[4], sum = 0;
#pragma unroll
    for (int k = 0; k < 4; ++k) {
        const int i = tid * 4 + k;
        v[k] = (i < NBINS) ? binCounts[i * CPAD] : 0;
        sum += v[k];
    }
    sdat[tid] = sum;
    __syncthreads();
    for (int d = 1; d < 512; d <<= 1) {
        const int t = (tid >= d) ? sdat[tid - d] : 0;
        __syncthreads();
        sdat[tid] += t;
        __syncthreads();
    }
    int run = sdat[tid] - sum;
#pragma unroll
    for (int k = 0; k < 4; ++k) {
        const int i = tid * 4 + k;
        if (i < NBINS) { binOff[i] = run; binCursor[i * CPAD] = run; }
        run += v[k];
    }
    if (tid == 511) binOff[NBINS] = sdat[511];
}

// ---------------- partition: pack (col,localrow,q9val) into u32, bin-grouped ----------------
__global__ __launch_bounds__(256) void partition_kernel(const int* __restrict__ erow,
                                                        const int* __restrict__ ecol,
                                                        const float* __restrict__ eval_,
                                                        int* __restrict__ binCursor,
                                                        u32* __restrict__ pedge, int ne) {
    __shared__ int h[NBINS];
    __shared__ int lcur[NBINS];
    for (int i = threadIdx.x; i < NBINS; i += 256) h[i] = 0;
    __syncthreads();
    const int base = blockIdx.x * PE;
    const int end  = min(base + PE, ne);
    for (int e = base + threadIdx.x; e < end; e += 256)
        atomicAdd(&h[erow[e] >> 6], 1);           // LDS, no-return
    __syncthreads();
    for (int i = threadIdx.x; i < NBINS; i += 256) {
        const int c = h[i];
        lcur[i] = c ? atomicAdd(&binCursor[i * CPAD], c) : 0;   // padded: ~123 RMW/line
    }
    __syncthreads();
    for (int e = base + threadIdx.x; e < end; e += 256) {
        const int r = erow[e];
        const int bin = r >> 6;
        const int pos = atomicAdd(&lcur[bin], 1);
        int q = (int)(eval_[e] * 512.0f + 0.5f);
        q = (q > 511) ? 511 : q;
        pedge[pos] = ((u32)ecol[e] << 15) | ((u32)(r & 63) << 9) | (u32)q;
    }
}

// ---------------- aggregate: one block per 64-row bin, 16KB int LDS acc ----------------
__global__ __launch_bounds__(256) void aggregate_kernel(const int* __restrict__ binOff,
                                                        const u32* __restrict__ pedge,
                                                        const unsigned short* __restrict__ y,
                                                        const float* __restrict__ b,
                                                        float4* __restrict__ out4) {
    __shared__ int acc[BIN_ROWS * D];    // 16 KB
    const int tid = threadIdx.x;
    for (int i = tid; i < BIN_ROWS * D; i += 256) acc[i] = 0;
    __syncthreads();

    const int bin  = blockIdx.x;
    const int lane = tid & 63;
    const int w    = tid >> 6;
    const int s    = binOff[bin];
    const int e    = binOff[bin + 1];

    for (int bb0 = s + w * 16; bb0 < e; bb0 += 64) {
        const int bb = __builtin_amdgcn_readfirstlane(bb0);
        u32 u[16];
#pragma unroll
        for (int j = 0; j < 16; ++j) {          // wave-uniform -> scalar loads
            const int idx = bb + j;
            const u32 t = pedge[(idx < e) ? idx : (e - 1)];
            u[j] = (idx < e) ? t : 0u;          // pad decodes to vq=0 -> adds 0
        }
        unsigned short g[16];
#pragma unroll
        for (int j = 0; j < 16; ++j) {          // 16 concurrent 128B row gathers
            g[j] = y[(int)(u[j] >> 15) * D + lane];
        }
#pragma unroll
        for (int j = 0; j < 16; ++j) {
            const float vq = (float)(u[j] & 511u);          // val * 512
            const float yf = bf16_to_f32(g[j]);
            const int   qi = (int)(vq * yf * 512.0f);       // contribution * 2^18
            const int   r  = (int)((u[j] >> 9) & 63u);
            atomicAdd(&acc[r * D + lane], qi);              // ds_add_u32 (native)
        }
    }
    __syncthreads();

    const int rowBase = bin * BIN_ROWS;
    const float INV = 1.0f / 262144.0f;
    for (int i = tid; i < BIN_ROWS * 16; i += 256) {
        const int rl = i >> 4, q = i & 15;
        const int row = rowBase + rl;
        if (row < N_NODES) {
            const int4   a  = ((const int4*)acc)[i];
            const float4 bv = ((const float4*)b)[q];
            out4[row * 16 + q] = make_float4((float)a.x * INV + bv.x,
                                             (float)a.y * INV + bv.y,
                                             (float)a.z * INV + bv.z,
                                             (float)a.w * INV + bv.w);
        }
    }
}

// ---------------- fallback (small ws): atomic scatter ----------------
__global__ __launch_bounds__(256) void init_out_kernel(const float* __restrict__ b,
                                                       float* __restrict__ out) {
    const int i = blockIdx.x * blockDim.x + threadIdx.x;
    const int total4 = N_NODES * D / 4;
    if (i < total4) {
        const float4* b4 = reinterpret_cast<const float4*>(b);
        reinterpret_cast<float4*>(out)[i] = b4[i & 15];
    }
}

__global__ __launch_bounds__(256) void scatter_kernel(const int* __restrict__ erow,
                                                      const int* __restrict__ ecol,
                                                      const float* __restrict__ eval_,
                                                      const unsigned short* __restrict__ y,
                                                      float* __restrict__ out, int ne) {
    const int e    = blockIdx.x * 4 + (threadIdx.x >> 6);
    const int lane = threadIdx.x & 63;
    if (e >= ne) return;
    atomicAdd(&out[erow[e] * D + lane], eval_[e] * bf16_to_f32(y[ecol[e] * D + lane]));
}

extern "C" void kernel_launch(void* const* d_in, const int* in_sizes, int n_in,
                              void* d_out, int out_size, void* d_ws, size_t ws_size,
                              hipStream_t stream) {
    const float* x     = (const float*)d_in[0];
    const int*   erow  = (const int*)  d_in[1];
    const int*   ecol  = (const int*)  d_in[2];
    const float* eval_ = (const float*)d_in[3];
    const float* W     = (const float*)d_in[4];
    const float* b     = (const float*)d_in[5];
    float*       out   = (float*)d_out;
    const int ne = in_sizes[1];

    char* ws = (char*)d_ws;
    // workspace layout (256-aligned)
    const size_t Y_OFF     = 0;              // 100000*64*2 = 12,800,000 B
    const size_t PEDGE_OFF = 12800000;       // 1M * 4B = 4,000,000 B
    const size_t BCNT_OFF  = 16800000;       // NBINS*16*4 = 100,032 B (padded)
    const size_t BOFF_OFF  = 16900096;       // 1564*4 = 6,256 B (dense)
    const size_t BCUR_OFF  = 16906496;       // 100,032 B (padded)
    const size_t TOTAL     = 17006592;

    unsigned short* y = (unsigned short*)(ws + Y_OFF);

    if (ws_size >= TOTAL) {
        u32* pedge     = (u32*)(ws + PEDGE_OFF);
        int* binCounts = (int*)(ws + BCNT_OFF);
        int* binOff    = (int*)(ws + BOFF_OFF);
        int* binCursor = (int*)(ws + BCUR_OFF);

        // 0) zero padded bin counters
        hipMemsetAsync(binCounts, 0, NBINS * CPAD * sizeof(int), stream);

        // 1) y = bf16(x @ W^T)
        xw_kernel<<<3125, 256, 0, stream>>>(x, W, y);

        // 2) coarse CSR (1563 bins of 64 rows), padded counters
        binhist_kernel<<<128, 256, 0, stream>>>(erow, binCounts, ne);
        binscan_kernel<<<1, 512, 0, stream>>>(binCounts, binOff, binCursor);
        partition_kernel<<<(ne + PE - 1) / PE, 256, 0, stream>>>(erow, ecol, eval_, binCursor, pedge, ne);

        // 3) per-bin int-LDS-accumulated aggregation + bias
        aggregate_kernel<<<NBINS, 256, 0, stream>>>(binOff, pedge, y, b, (float4*)out);
    } else {
        xw_kernel<<<3125, 256, 0, stream>>>(x, W, y);
        init_out_kernel<<<(N_NODES * D / 4 + 255) / 256, 256, 0, stream>>>(b, out);
        scatter_kernel<<<(ne + 3) / 4, 256, 0, stream>>>(erow, ecol, eval_, y, out, ne);
    }
}

// Round 9
// 110.650 us; speedup vs baseline: 2.1257x; 1.2743x over previous
//
#include <hip/hip_runtime.h>

#define N_NODES 100000
#define D 64
#define BIN_ROWS 64
#define NBINS 1563          // ceil(100000 / 64)
#define PE 2048             // edges per partition block -> 489 blocks @ 1M edges

typedef unsigned int u32;

__device__ __forceinline__ float bf16_to_f32(unsigned short u) {
    union { u32 i; float f; } c; c.i = ((u32)u) << 16; return c.f;
}
__device__ __forceinline__ unsigned short f32_to_bf16(float f) {
    union { float f; u32 i; } c; c.f = f;
    const u32 u = c.i;
    return (unsigned short)((u + 0x7FFFu + ((u >> 16) & 1u)) >> 16);
}

// ---------------- y = bf16(x @ W^T) ----------------
__global__ __launch_bounds__(256) void xw_kernel(const float* __restrict__ x,
                                                 const float* __restrict__ W,
                                                 unsigned short* __restrict__ y) {
    __shared__ float Ws[D][D + 1];
    __shared__ float xs[32][D];
    const int tid = threadIdx.x;

    for (int i = tid; i < D * D; i += 256) Ws[i >> 6][i & 63] = W[i];

    const int nodeBase = blockIdx.x * 32;     // N_NODES = 3125*32 exactly
    for (int i = tid; i < 32 * D; i += 256)
        xs[i >> 6][i & 63] = x[(nodeBase + (i >> 6)) * D + (i & 63)];
    __syncthreads();

    const int wave = tid >> 6, j = tid & 63;
    for (int s = 0; s < 8; ++s) {
        const int local = wave * 8 + s;
        float acc = 0.f;
#pragma unroll
        for (int k = 0; k < D; ++k) acc += xs[local][k] * Ws[j][k];
        y[(nodeBase + local) * D + j] = f32_to_bf16(acc);
    }
}

// ---------------- per-block LDS histogram -> dense hist2d[block][NBINS] ----------------
__global__ __launch_bounds__(256) void binhist_kernel(const int* __restrict__ erow,
                                                      int* __restrict__ hist2d, int ne) {
    __shared__ int h[NBINS];
    for (int i = threadIdx.x; i < NBINS; i += 256) h[i] = 0;
    __syncthreads();
    const int base = blockIdx.x * PE;
    const int end  = min(base + PE, ne);
    for (int e = base + threadIdx.x; e < end; e += 256)
        atomicAdd(&h[erow[e] >> 6], 1);
    __syncthreads();
    for (int i = threadIdx.x; i < NBINS; i += 256)
        hist2d[blockIdx.x * NBINS + i] = h[i];       // coalesced, no atomics
}

// ---------------- scan over hist2d in bin-major order: idx = bin*npb + blk ----------------
// scanA: per-1024 block scan (exclusive within block) + block sums
__global__ __launch_bounds__(256) void scanA_kernel(const int* __restrict__ hist2d,
                                                    int* __restrict__ scan2d,
                                                    int* __restrict__ bsum,
                                                    int total, int npb) {
    __shared__ int sdat[256];
    const int tid  = threadIdx.x;
    const int base = blockIdx.x * 1024 + tid * 4;
    int v[4], sum = 0;
    int bin = 0, blk = 0;
    if (base < total) { bin = base / npb; blk = base - bin * npb; }
#pragma unroll
    for (int k = 0; k < 4; ++k) {
        const int idx = base + k;
        v[k] = (idx < total) ? hist2d[blk * NBINS + bin] : 0;
        sum += v[k];
        if (++blk == npb) { blk = 0; ++bin; }
    }
    sdat[tid] = sum;
    __syncthreads();
    for (int d = 1; d < 256; d <<= 1) {
        const int t = (tid >= d) ? sdat[tid - d] : 0;
        __syncthreads();
        sdat[tid] += t;
        __syncthreads();
    }
    int run = sdat[tid] - sum;
#pragma unroll
    for (int k = 0; k < 4; ++k) {
        const int idx = base + k;
        if (idx < total) scan2d[idx] = run;
        run += v[k];
    }
    if (tid == 255) bsum[blockIdx.x] = sdat[255];
}

// scanB: single block exclusive scan of up to 2048 block sums
__global__ __launch_bounds__(1024) void scanB_kernel(int* __restrict__ bsum, int nb) {
    __shared__ int s[1024];
    const int tid = threadIdx.x;
    const int a = (2 * tid     < nb) ? bsum[2 * tid]     : 0;
    const int b = (2 * tid + 1 < nb) ? bsum[2 * tid + 1] : 0;
    const int pair = a + b;
    s[tid] = pair;
    __syncthreads();
    for (int d = 1; d < 1024; d <<= 1) {
        const int t = (tid >= d) ? s[tid - d] : 0;
        __syncthreads();
        s[tid] += t;
        __syncthreads();
    }
    const int excl = s[tid] - pair;
    if (2 * tid     < nb) bsum[2 * tid]     = excl;
    if (2 * tid + 1 < nb) bsum[2 * tid + 1] = excl + a;
}

// scanC: add block offsets in place
__global__ __launch_bounds__(256) void scanC_kernel(int* __restrict__ scan2d,
                                                    const int* __restrict__ bsum, int total) {
    const int add  = bsum[blockIdx.x];
    const int base = blockIdx.x * 1024 + threadIdx.x * 4;
#pragma unroll
    for (int k = 0; k < 4; ++k) {
        const int idx = base + k;
        if (idx < total) scan2d[idx] += add;
    }
}

// ---------------- partition: precomputed cursors, single store pass ----------------
__global__ __launch_bounds__(256) void partition_kernel(const int* __restrict__ erow,
                                                        const int* __restrict__ ecol,
                                                        const float* __restrict__ eval_,
                                                        const int* __restrict__ scan2d,
                                                        u32* __restrict__ pedge,
                                                        int ne, int npb) {
    __shared__ int lcur[NBINS];
    const int blk = blockIdx.x;
    for (int i = threadIdx.x; i < NBINS; i += 256)
        lcur[i] = scan2d[i * npb + blk];             // strided gather, L2-resident
    __syncthreads();
    const int base = blk * PE;
    const int end  = min(base + PE, ne);
    for (int e = base + threadIdx.x; e < end; e += 256) {
        const int r   = erow[e];
        const int bin = r >> 6;
        const int pos = atomicAdd(&lcur[bin], 1);    // LDS-local, returns rank
        int q = (int)(eval_[e] * 512.0f + 0.5f);
        q = (q > 511) ? 511 : q;
        pedge[pos] = ((u32)ecol[e] << 15) | ((u32)(r & 63) << 9) | (u32)q;
    }
}

// ---------------- aggregate: one block per 64-row bin, 16KB int LDS acc ----------------
__global__ __launch_bounds__(256) void aggregate_kernel(const int* __restrict__ scan2d,
                                                        const u32* __restrict__ pedge,
                                                        const unsigned short* __restrict__ y,
                                                        const float* __restrict__ b,
                                                        float4* __restrict__ out4,
                                                        int ne, int npb) {
    __shared__ int acc[BIN_ROWS * D];    // 16 KB
    const int tid = threadIdx.x;
    for (int i = tid; i < BIN_ROWS * D; i += 256) acc[i] = 0;
    __syncthreads();

    const int bin  = blockIdx.x;
    const int lane = tid & 63;
    const int w    = tid >> 6;
    const int s    = scan2d[bin * npb];
    const int e    = (bin + 1 < NBINS) ? scan2d[(bin + 1) * npb] : ne;

    for (int bb0 = s + w * 16; bb0 < e; bb0 += 64) {
        const int bb = __builtin_amdgcn_readfirstlane(bb0);
        u32 u[16];
#pragma unroll
        for (int j = 0; j < 16; ++j) {          // wave-uniform -> scalar loads
            const int idx = bb + j;
            const u32 t = pedge[(idx < e) ? idx : (e - 1)];
            u[j] = (idx < e) ? t : 0u;          // pad decodes to vq=0 -> adds 0
        }
        unsigned short g[16];
#pragma unroll
        for (int j = 0; j < 16; ++j) {          // 16 concurrent 128B row gathers
            g[j] = y[(int)(u[j] >> 15) * D + lane];
        }
#pragma unroll
        for (int j = 0; j < 16; ++j) {
            const float vq = (float)(u[j] & 511u);          // val * 512
            const float yf = bf16_to_f32(g[j]);
            const int   qi = (int)(vq * yf * 512.0f);       // contribution * 2^18
            const int   r  = (int)((u[j] >> 9) & 63u);
            atomicAdd(&acc[r * D + lane], qi);              // ds_add_u32 (native)
        }
    }
    __syncthreads();

    const int rowBase = bin * BIN_ROWS;
    const float INV = 1.0f / 262144.0f;
    for (int i = tid; i < BIN_ROWS * 16; i += 256) {
        const int rl = i >> 4, q = i & 15;
        const int row = rowBase + rl;
        if (row < N_NODES) {
            const int4   a  = ((const int4*)acc)[i];
            const float4 bv = ((const float4*)b)[q];
            out4[row * 16 + q] = make_float4((float)a.x * INV + bv.x,
                                             (float)a.y * INV + bv.y,
                                             (float)a.z * INV + bv.z,
                                             (float)a.w * INV + bv.w);
        }
    }
}

// ---------------- fallback (small ws): atomic scatter ----------------
__global__ __launch_bounds__(256) void init_out_kernel(const float* __restrict__ b,
                                                       float* __restrict__ out) {
    const int i = blockIdx.x * blockDim.x + threadIdx.x;
    const int total4 = N_NODES * D / 4;
    if (i < total4) {
        const float4* b4 = reinterpret_cast<const float4*>(b);
        reinterpret_cast<float4*>(out)[i] = b4[i & 15];
    }
}

__global__ __launch_bounds__(256) void scatter_kernel(const int* __restrict__ erow,
                                                      const int* __restrict__ ecol,
                                                      const float* __restrict__ eval_,
                                                      const unsigned short* __restrict__ y,
                                                      float* __restrict__ out, int ne) {
    const int e    = blockIdx.x * 4 + (threadIdx.x >> 6);
    const int lane = threadIdx.x & 63;
    if (e >= ne) return;
    atomicAdd(&out[erow[e] * D + lane], eval_[e] * bf16_to_f32(y[ecol[e] * D + lane]));
}

extern "C" void kernel_launch(void* const* d_in, const int* in_sizes, int n_in,
                              void* d_out, int out_size, void* d_ws, size_t ws_size,
                              hipStream_t stream) {
    const float* x     = (const float*)d_in[0];
    const int*   erow  = (const int*)  d_in[1];
    const int*   ecol  = (const int*)  d_in[2];
    const float* eval_ = (const float*)d_in[3];
    const float* W     = (const float*)d_in[4];
    const float* b     = (const float*)d_in[5];
    float*       out   = (float*)d_out;
    const int ne = in_sizes[1];

    char* ws = (char*)d_ws;
    // workspace layout (aligned)
    const size_t Y_OFF    = 0;             // 12,800,000 B
    const size_t PEDGE_OFF= 12800000;      // 4,000,000 B
    const size_t H2D_OFF  = 16800000;      // up to 4,000,000 B (npb*NBINS*4)
    const size_t SCAN_OFF = 20800000;      // up to 4,000,000 B
    const size_t BSUM_OFF = 24800000;      // 8,192 B
    const size_t TOTAL    = 24808192;

    unsigned short* y = (unsigned short*)(ws + Y_OFF);

    const int npb      = (ne + PE - 1) / PE;       // 489 @ 1M edges
    const int totalSc  = NBINS * npb;              // 764,307
    const int nblocksA = (totalSc + 1023) / 1024;  // 747

    if (ws_size >= TOTAL && npb <= 1341) {         // bsum cap 2048, scan fits
        u32* pedge  = (u32*)(ws + PEDGE_OFF);
        int* hist2d = (int*)(ws + H2D_OFF);
        int* scan2d = (int*)(ws + SCAN_OFF);
        int* bsum   = (int*)(ws + BSUM_OFF);

        // 1) y = bf16(x @ W^T)
        xw_kernel<<<3125, 256, 0, stream>>>(x, W, y);

        // 2) per-block histograms (dense, atomic-free output)
        binhist_kernel<<<npb, 256, 0, stream>>>(erow, hist2d, ne);

        // 3) bin-major exclusive scan -> deterministic per-(bin,block) offsets
        scanA_kernel<<<nblocksA, 256, 0, stream>>>(hist2d, scan2d, bsum, totalSc, npb);
        scanB_kernel<<<1, 1024, 0, stream>>>(bsum, nblocksA);
        scanC_kernel<<<nblocksA, 256, 0, stream>>>(scan2d, bsum, totalSc);

        // 4) partition: single store pass, no global atomics
        partition_kernel<<<npb, 256, 0, stream>>>(erow, ecol, eval_, scan2d, pedge, ne, npb);

        // 5) per-bin int-LDS-accumulated aggregation + bias
        aggregate_kernel<<<NBINS, 256, 0, stream>>>(scan2d, pedge, y, b, (float4*)out, ne, npb);
    } else {
        xw_kernel<<<3125, 256, 0, stream>>>(x, W, y);
        init_out_kernel<<<(N_NODES * D / 4 + 255) / 256, 256, 0, stream>>>(b, out);
        scatter_kernel<<<(ne + 3) / 4, 256, 0, stream>>>(erow, ecol, eval_, y, out, ne);
    }
}

// Round 10
// 79.697 us; speedup vs baseline: 2.9514x; 1.3884x over previous
//
#include <hip/hip_runtime.h>

#define N_NODES 100000
#define D 64
#define BIN_ROWS 64
#define NBINS 1563          // ceil(100000 / 64)
#define PE 2048             // edges per partition/hist block
#define XWB 3125            // xw blocks (100000 / 32)

typedef unsigned int u32;

__device__ __forceinline__ float bf16_to_f32(unsigned short u) {
    union { u32 i; float f; } c; c.i = ((u32)u) << 16; return c.f;
}
__device__ __forceinline__ unsigned short f32_to_bf16(float f) {
    union { float f; u32 i; } c; c.f = f;
    const u32 u = c.i;
    return (unsigned short)((u + 0x7FFFu + ((u >> 16) & 1u)) >> 16);
}

// ---------------- K1: fused  y = bf16(x @ W^T)  (blocks < XWB)
// ----------------            per-block bin histogram (blocks >= XWB) ----------------
__global__ __launch_bounds__(256) void xw_hist_kernel(const float* __restrict__ x,
                                                      const float* __restrict__ W,
                                                      unsigned short* __restrict__ y,
                                                      const int* __restrict__ erow,
                                                      int* __restrict__ hist2d, int ne) {
    __shared__ union {
        struct { float Ws[D * 68]; float xs[32][D]; } g;   // 17408 + 8192 B
        int h[NBINS];                                      // 6252 B
    } sm;
    const int tid = threadIdx.x;

    if (blockIdx.x >= XWB) {
        // ---- binhist part: dense per-block histogram, no global atomics ----
        const int blk = blockIdx.x - XWB;
        for (int i = tid; i < NBINS; i += 256) sm.h[i] = 0;
        __syncthreads();
        const int base = blk * PE;
        const int end  = min(base + PE, ne);
        for (int e = base + tid; e < end; e += 256)
            atomicAdd(&sm.h[erow[e] >> 6], 1);             // LDS, no-return
        __syncthreads();
        for (int i = tid; i < NBINS; i += 256)
            hist2d[blk * NBINS + i] = sm.h[i];             // coalesced
        return;
    }

    // ---- xw part: W register-resident, x via LDS broadcast ----
    for (int i = tid; i < D * D; i += 256)
        sm.g.Ws[(i >> 6) * 68 + (i & 63)] = W[i];          // stride 68: 16B-aligned rows

    const int nodeBase = blockIdx.x * 32;                  // N_NODES = 3125*32 exactly
    for (int i = tid; i < 32 * D; i += 256)
        sm.g.xs[i >> 6][i & 63] = x[(nodeBase + (i >> 6)) * D + (i & 63)];
    __syncthreads();

    const int j = tid & 63, w = tid >> 6;
    float4 wr[16];
    const float4* WsRow = (const float4*)(sm.g.Ws + j * 68);
#pragma unroll
    for (int k = 0; k < 16; ++k) wr[k] = WsRow[k];

    for (int s = 0; s < 8; ++s) {
        const int local = w * 8 + s;
        const float4* xr = (const float4*)(&sm.g.xs[local][0]);   // wave-broadcast reads
        float a0 = 0.f, a1 = 0.f, a2 = 0.f, a3 = 0.f;
#pragma unroll
        for (int k = 0; k < 16; k += 4) {
            const float4 x0 = xr[k], x1 = xr[k+1], x2 = xr[k+2], x3 = xr[k+3];
            a0 = fmaf(x0.x, wr[k].x, a0);   a0 = fmaf(x0.y, wr[k].y, a0);
            a0 = fmaf(x0.z, wr[k].z, a0);   a0 = fmaf(x0.w, wr[k].w, a0);
            a1 = fmaf(x1.x, wr[k+1].x, a1); a1 = fmaf(x1.y, wr[k+1].y, a1);
            a1 = fmaf(x1.z, wr[k+1].z, a1); a1 = fmaf(x1.w, wr[k+1].w, a1);
            a2 = fmaf(x2.x, wr[k+2].x, a2); a2 = fmaf(x2.y, wr[k+2].y, a2);
            a2 = fmaf(x2.z, wr[k+2].z, a2); a2 = fmaf(x2.w, wr[k+2].w, a2);
            a3 = fmaf(x3.x, wr[k+3].x, a3); a3 = fmaf(x3.y, wr[k+3].y, a3);
            a3 = fmaf(x3.z, wr[k+3].z, a3); a3 = fmaf(x3.w, wr[k+3].w, a3);
        }
        y[(nodeBase + local) * D + j] = f32_to_bf16((a0 + a1) + (a2 + a3));
    }
}

// ---------------- scanA: per-1024-chunk exclusive scan (bin-major index) + chunk sums ----------------
__global__ __launch_bounds__(256) void scanA_kernel(const int* __restrict__ hist2d,
                                                    int* __restrict__ scan2d,
                                                    int* __restrict__ bsum,
                                                    int total, int npb) {
    __shared__ int sdat[256];
    const int tid  = threadIdx.x;
    const int base = blockIdx.x * 1024 + tid * 4;
    int v[4], sum = 0;
    int bin = 0, blk = 0;
    if (base < total) { bin = base / npb; blk = base - bin * npb; }
#pragma unroll
    for (int k = 0; k < 4; ++k) {
        const int idx = base + k;
        v[k] = (idx < total) ? hist2d[blk * NBINS + bin] : 0;
        sum += v[k];
        if (++blk == npb) { blk = 0; ++bin; }
    }
    sdat[tid] = sum;
    __syncthreads();
    for (int d = 1; d < 256; d <<= 1) {
        const int t = (tid >= d) ? sdat[tid - d] : 0;
        __syncthreads();
        sdat[tid] += t;
        __syncthreads();
    }
    int run = sdat[tid] - sum;
#pragma unroll
    for (int k = 0; k < 4; ++k) {
        const int idx = base + k;
        if (idx < total) scan2d[idx] = run;
        run += v[k];
    }
    if (tid == 255) bsum[blockIdx.x] = sdat[255];
}

// ---------------- scanB: single-block exclusive scan of chunk sums (in place) ----------------
__global__ __launch_bounds__(1024) void scanB_kernel(int* __restrict__ bsum, int nb) {
    __shared__ int s[1024];
    const int tid = threadIdx.x;
    const int a = (2 * tid     < nb) ? bsum[2 * tid]     : 0;
    const int b = (2 * tid + 1 < nb) ? bsum[2 * tid + 1] : 0;
    const int pair = a + b;
    s[tid] = pair;
    __syncthreads();
    for (int d = 1; d < 1024; d <<= 1) {
        const int t = (tid >= d) ? s[tid - d] : 0;
        __syncthreads();
        s[tid] += t;
        __syncthreads();
    }
    const int excl = s[tid] - pair;
    if (2 * tid     < nb) bsum[2 * tid]     = excl;
    if (2 * tid + 1 < nb) bsum[2 * tid + 1] = excl + a;
}

// ---------------- partition: precomputed cursors (scan2d + bsum), single store pass ----------------
__global__ __launch_bounds__(256) void partition_kernel(const int* __restrict__ erow,
                                                        const int* __restrict__ ecol,
                                                        const float* __restrict__ eval_,
                                                        const int* __restrict__ scan2d,
                                                        const int* __restrict__ bsum,
                                                        u32* __restrict__ pedge,
                                                        int ne, int npb) {
    __shared__ int lcur[NBINS];
    const int blk = blockIdx.x;
    for (int i = threadIdx.x; i < NBINS; i += 256) {
        const int idx = i * npb + blk;
        lcur[i] = scan2d[idx] + bsum[idx >> 10];
    }
    __syncthreads();
    const int base = blk * PE;
    const int end  = min(base + PE, ne);
    for (int e = base + threadIdx.x; e < end; e += 256) {
        const int r   = erow[e];
        const int bin = r >> 6;
        const int pos = atomicAdd(&lcur[bin], 1);    // LDS-local rank
        int q = (int)(eval_[e] * 512.0f + 0.5f);
        q = (q > 511) ? 511 : q;
        pedge[pos] = ((u32)ecol[e] << 15) | ((u32)(r & 63) << 9) | (u32)q;
    }
}

// ---------------- aggregate: one 512-thread block per 64-row bin, 16KB int LDS acc ----------------
__global__ __launch_bounds__(512) void aggregate_kernel(const int* __restrict__ scan2d,
                                                        const int* __restrict__ bsum,
                                                        const u32* __restrict__ pedge,
                                                        const unsigned short* __restrict__ y,
                                                        const float* __restrict__ b,
                                                        float4* __restrict__ out4,
                                                        int ne, int npb) {
    __shared__ int acc[BIN_ROWS * D];    // 16 KB
    const int tid = threadIdx.x;
    for (int i = tid; i < BIN_ROWS * D; i += 512) acc[i] = 0;
    __syncthreads();

    const int bin  = blockIdx.x;
    const int lane = tid & 63;
    const int w    = tid >> 6;           // 0..7
    const int i0   = bin * npb;
    const int s    = scan2d[i0] + bsum[i0 >> 10];
    int e;
    if (bin + 1 < NBINS) {
        const int i1 = (bin + 1) * npb;
        e = scan2d[i1] + bsum[i1 >> 10];
    } else {
        e = ne;
    }

    for (int bb0 = s + w * 16; bb0 < e; bb0 += 128) {
        const int bb = __builtin_amdgcn_readfirstlane(bb0);
        u32 u[16];
        if (bb + 16 <= e) {
#pragma unroll
            for (int j = 0; j < 16; ++j) u[j] = pedge[bb + j];   // consecutive scalar loads
        } else {
#pragma unroll
            for (int j = 0; j < 16; ++j) {
                const int idx = bb + j;
                u[j] = (idx < e) ? pedge[idx] : 0u;              // pad adds 0
            }
        }
        unsigned short g[16];
#pragma unroll
        for (int j = 0; j < 16; ++j) {                           // 16 concurrent 128B gathers
            g[j] = y[(int)(u[j] >> 15) * D + lane];
        }
#pragma unroll
        for (int j = 0; j < 16; ++j) {
            const float vq = (float)(u[j] & 511u);               // val * 512
            const float yf = bf16_to_f32(g[j]);
            const int   qi = (int)(vq * yf * 512.0f);            // contribution * 2^18
            const int   r  = (int)((u[j] >> 9) & 63u);
            atomicAdd(&acc[r * D + lane], qi);                   // ds_add_u32 (native)
        }
    }
    __syncthreads();

    const int rowBase = bin * BIN_ROWS;
    const float INV = 1.0f / 262144.0f;
    for (int i = tid; i < BIN_ROWS * 16; i += 512) {
        const int rl = i >> 4, q = i & 15;
        const int row = rowBase + rl;
        if (row < N_NODES) {
            const int4   a  = ((const int4*)acc)[i];
            const float4 bv = ((const float4*)b)[q];
            out4[row * 16 + q] = make_float4((float)a.x * INV + bv.x,
                                             (float)a.y * INV + bv.y,
                                             (float)a.z * INV + bv.z,
                                             (float)a.w * INV + bv.w);
        }
    }
}

// ---------------- fallback (small ws): atomic scatter ----------------
__global__ __launch_bounds__(256) void init_out_kernel(const float* __restrict__ b,
                                                       float* __restrict__ out) {
    const int i = blockIdx.x * blockDim.x + threadIdx.x;
    const int total4 = N_NODES * D / 4;
    if (i < total4) {
        const float4* b4 = reinterpret_cast<const float4*>(b);
        reinterpret_cast<float4*>(out)[i] = b4[i & 15];
    }
}

__global__ __launch_bounds__(256) void scatter_kernel(const int* __restrict__ erow,
                                                      const int* __restrict__ ecol,
                                                      const float* __restrict__ eval_,
                                                      const unsigned short* __restrict__ y,
                                                      float* __restrict__ out, int ne) {
    const int e    = blockIdx.x * 4 + (threadIdx.x >> 6);
    const int lane = threadIdx.x & 63;
    if (e >= ne) return;
    atomicAdd(&out[erow[e] * D + lane], eval_[e] * bf16_to_f32(y[ecol[e] * D + lane]));
}

extern "C" void kernel_launch(void* const* d_in, const int* in_sizes, int n_in,
                              void* d_out, int out_size, void* d_ws, size_t ws_size,
                              hipStream_t stream) {
    const float* x     = (const float*)d_in[0];
    const int*   erow  = (const int*)  d_in[1];
    const int*   ecol  = (const int*)  d_in[2];
    const float* eval_ = (const float*)d_in[3];
    const float* W     = (const float*)d_in[4];
    const float* b     = (const float*)d_in[5];
    float*       out   = (float*)d_out;
    const int ne = in_sizes[1];

    char* ws = (char*)d_ws;
    // workspace layout (aligned)
    const size_t Y_OFF    = 0;             // 12,800,000 B
    const size_t PEDGE_OFF= 12800000;      // 4,000,000 B
    const size_t H2D_OFF  = 16800000;      // up to 4,000,000 B (npb*NBINS*4)
    const size_t SCAN_OFF = 20800000;      // up to 4,000,000 B
    const size_t BSUM_OFF = 24800000;      // 8,192 B
    const size_t TOTAL    = 24808192;

    unsigned short* y = (unsigned short*)(ws + Y_OFF);

    const int npb      = (ne + PE - 1) / PE;       // 489 @ 1M edges
    const int totalSc  = NBINS * npb;              // 764,307
    const int nblocksA = (totalSc + 1023) / 1024;  // 747 (<= 2048 for scanB)

    if (ws_size >= TOTAL && npb <= 1341) {
        u32* pedge  = (u32*)(ws + PEDGE_OFF);
        int* hist2d = (int*)(ws + H2D_OFF);
        int* scan2d = (int*)(ws + SCAN_OFF);
        int* bsum   = (int*)(ws + BSUM_OFF);

        // 1) fused: y = bf16(x @ W^T)  ||  per-block bin histograms
        xw_hist_kernel<<<XWB + npb, 256, 0, stream>>>(x, W, y, erow, hist2d, ne);

        // 2) bin-major exclusive scan (chunk-local) + chunk sums
        scanA_kernel<<<nblocksA, 256, 0, stream>>>(hist2d, scan2d, bsum, totalSc, npb);
        scanB_kernel<<<1, 1024, 0, stream>>>(bsum, nblocksA);

        // 3) partition: single store pass, no global atomics (bsum folded at read)
        partition_kernel<<<npb, 256, 0, stream>>>(erow, ecol, eval_, scan2d, bsum, pedge, ne, npb);

        // 4) per-bin int-LDS-accumulated aggregation + bias (8 waves/block)
        aggregate_kernel<<<NBINS, 512, 0, stream>>>(scan2d, bsum, pedge, y, b, (float4*)out, ne, npb);
    } else {
        xw_hist_kernel<<<XWB, 256, 0, stream>>>(x, W, y, erow, (int*)ws, 0);
        init_out_kernel<<<(N_NODES * D / 4 + 255) / 256, 256, 0, stream>>>(b, out);
        scatter_kernel<<<(ne + 3) / 4, 256, 0, stream>>>(erow, ecol, eval_, y, out, ne);
    }
}